// Round 2
// baseline (432.853 us; speedup 1.0000x reference)
//
#include <hip/hip_runtime.h>
#include <hip/hip_bf16.h>
#include <stdint.h>

#define DMODEL 256
#define BATCH  16
#define MEL    2048
#define SRC    512
#define TB     16
#define SPAD   2052   // 2048 + 4 pad: breaks LDS bank aliasing on row-strided reads

typedef __attribute__((ext_vector_type(8))) short bf16x8;
typedef __attribute__((ext_vector_type(4))) float f32x4;

__device__ inline short f2bf(float f) {
    union { float f; uint32_t u; } c{f};
    uint32_t u = c.u;
    u += 0x7FFFu + ((u >> 16) & 1u);   // round-to-nearest-even
    return (short)(u >> 16);
}

__device__ inline bf16x8 load8_f32_to_bf16(const float* p) {
    const f32x4* q = reinterpret_cast<const f32x4*>(p);
    f32x4 a = q[0], b = q[1];
    bf16x8 r;
    r[0] = f2bf(a[0]); r[1] = f2bf(a[1]); r[2] = f2bf(a[2]); r[3] = f2bf(a[3]);
    r[4] = f2bf(b[0]); r[5] = f2bf(b[1]); r[6] = f2bf(b[2]); r[7] = f2bf(b[3]);
    return r;
}

// C[M][N] = A (M x 256, row-major f32) * Bt^T  (Bt is [N][256] row-major f32)
// Output bf16 (as short bits), row stride cstride.
// grid.x = M/64, grid.y = N/64, grid.z = batch; block = 256 threads (4 waves).
// Wave w computes rows [64*bx + 16w, +16), all 64 cols of the block tile.
__global__ __launch_bounds__(256)
void proj_kernel(const float* __restrict__ A, const float* __restrict__ Bt,
                 short* __restrict__ C, int cstride,
                 long abatch, long btbatch, long cbatch) {
    A  += (long)blockIdx.z * abatch;
    Bt += (long)blockIdx.z * btbatch;
    C  += (long)blockIdx.z * cbatch;

    const int lane = threadIdx.x & 63;
    const int w    = threadIdx.x >> 6;
    const int lr   = lane & 15;      // A row / B col within tile
    const int lk   = lane >> 4;      // k-group
    const int row_base = blockIdx.x * 64 + w * 16;
    const int col_base = blockIdx.y * 64;

    // A fragments for this wave's 16 rows, full K=256 (8 k-steps of 32)
    bf16x8 afr[8];
    const float* arow = A + (size_t)(row_base + lr) * DMODEL + 8 * lk;
#pragma unroll
    for (int t = 0; t < 8; ++t) afr[t] = load8_f32_to_bf16(arow + 32 * t);

#pragma unroll
    for (int n = 0; n < 4; ++n) {
        f32x4 acc = {0.f, 0.f, 0.f, 0.f};
        const float* brow = Bt + (size_t)(col_base + 16 * n + lr) * DMODEL + 8 * lk;
#pragma unroll
        for (int t = 0; t < 8; ++t) {
            bf16x8 bfr = load8_f32_to_bf16(brow + 32 * t);
            acc = __builtin_amdgcn_mfma_f32_16x16x32_bf16(afr[t], bfr, acc, 0, 0, 0);
        }
        // C/D layout: col = lane&15, row = (lane>>4)*4 + r
#pragma unroll
        for (int r = 0; r < 4; ++r) {
            C[(size_t)(row_base + lk * 4 + r) * cstride + col_base + 16 * n + lr] =
                f2bf(acc[r]);
        }
    }
}

// Fused attention: one block per (batch b, 16 query rows).
// Phase 1: S = q k^T / 16 (+ mel mask) -> LDS [16][2052] f32
// Phase 2: row softmax in LDS (+ src-mask zeroing), copy attn rows to d_out
// Phase 3: PV via MFMA (P from LDS -> bf16, v^T from global)
// Phase 4: LayerNorm + output write
__global__ __launch_bounds__(256)
void attn_kernel(const short* __restrict__ qbf, const short* __restrict__ kbf,
                 const short* __restrict__ vt,
                 const int* __restrict__ mel_mask, const int* __restrict__ src_mask,
                 const float* __restrict__ gamma, const float* __restrict__ beta,
                 float* __restrict__ out, float* __restrict__ attn_out) {
    __shared__ float S[TB * SPAD];   // 131,328 bytes

    const int tid  = threadIdx.x;
    const int lane = tid & 63;
    const int w    = tid >> 6;
    const int lr   = lane & 15;
    const int lk   = lane >> 4;
    const int b      = blockIdx.y;
    const int t_base = blockIdx.x * TB;

    // ---- q fragments (16 rows, K=256) ----
    bf16x8 qfr[8];
    const short* qrow = qbf + (size_t)(b * SRC + t_base + lr) * DMODEL + 8 * lk;
#pragma unroll
    for (int t = 0; t < 8; ++t)
        qfr[t] = *reinterpret_cast<const bf16x8*>(qrow + 32 * t);

    // ---- Phase 1: S tiles. Wave w covers s in [512w, 512w+512) ----
    const int s0 = w * 512;
    for (int tile = 0; tile < 32; ++tile) {
        f32x4 acc = {0.f, 0.f, 0.f, 0.f};
        const short* krow = kbf + (size_t)(b * MEL + s0 + tile * 16 + lr) * DMODEL + 8 * lk;
#pragma unroll
        for (int t = 0; t < 8; ++t) {
            bf16x8 kfr = *reinterpret_cast<const bf16x8*>(krow + 32 * t);
            acc = __builtin_amdgcn_mfma_f32_16x16x32_bf16(qfr[t], kfr, acc, 0, 0, 0);
        }
        const int col = s0 + tile * 16 + lr;
        const bool masked = mel_mask[b * MEL + col] != 0;
#pragma unroll
        for (int r = 0; r < 4; ++r) {
            float v = masked ? -1e30f : acc[r] * 0.0625f;   // 1/sqrt(256)
            S[(lk * 4 + r) * SPAD + col] = v;
        }
    }
    __syncthreads();

    // ---- Phase 2: softmax. Wave w owns rows 4w..4w+3; 16 lanes per row ----
    {
        const int row = 4 * w + lk;
        float* srow = S + row * SPAD;
        float m = -3.0e38f;
        for (int i = lr; i < MEL; i += 16) m = fmaxf(m, srow[i]);
#pragma unroll
        for (int off = 8; off; off >>= 1) m = fmaxf(m, __shfl_xor(m, off));
        float sum = 0.f;
        for (int i = lr; i < MEL; i += 16) {
            float e = __expf(srow[i] - m);
            srow[i] = e;
            sum += e;
        }
#pragma unroll
        for (int off = 8; off; off >>= 1) sum += __shfl_xor(sum, off);
        float inv = src_mask[b * SRC + t_base + row] ? 0.f : 1.f / sum;
        for (int i = lr; i < MEL; i += 16) srow[i] *= inv;
    }
    __syncthreads();

    // ---- Phase 2b: coalesced copy of attn tile to global ----
    {
        float* gbase = attn_out + (size_t)(b * SRC + t_base) * MEL;
        for (int r = 0; r < TB; ++r) {
            const f32x4* lrow = reinterpret_cast<const f32x4*>(S + r * SPAD);
            f32x4* grow = reinterpret_cast<f32x4*>(gbase + (size_t)r * MEL);
#pragma unroll
            for (int h = 0; h < 2; ++h) grow[tid + 256 * h] = lrow[tid + 256 * h];
        }
    }

    // ---- Phase 3: PV. Wave w covers out cols [64w, 64w+64) ----
    f32x4 pacc[4];
#pragma unroll
    for (int n = 0; n < 4; ++n) pacc[n] = (f32x4){0.f, 0.f, 0.f, 0.f};
    for (int ks = 0; ks < MEL / 32; ++ks) {
        const float* sp = S + lr * SPAD + 32 * ks + 8 * lk;
        f32x4 x0 = *reinterpret_cast<const f32x4*>(sp);
        f32x4 x1 = *reinterpret_cast<const f32x4*>(sp + 4);
        bf16x8 af;
        af[0] = f2bf(x0[0]); af[1] = f2bf(x0[1]); af[2] = f2bf(x0[2]); af[3] = f2bf(x0[3]);
        af[4] = f2bf(x1[0]); af[5] = f2bf(x1[1]); af[6] = f2bf(x1[2]); af[7] = f2bf(x1[3]);
#pragma unroll
        for (int n = 0; n < 4; ++n) {
            const short* vrow = vt + (size_t)(b * DMODEL + w * 64 + n * 16 + lr) * MEL + 32 * ks + 8 * lk;
            bf16x8 vfr = *reinterpret_cast<const bf16x8*>(vrow);
            pacc[n] = __builtin_amdgcn_mfma_f32_16x16x32_bf16(af, vfr, pacc[n], 0, 0, 0);
        }
    }
    __syncthreads();   // everyone done reading S before reuse

    // ---- Phase 4: stage out tile in LDS (stride 257), LayerNorm, write ----
    float* O = S;
#pragma unroll
    for (int n = 0; n < 4; ++n)
#pragma unroll
        for (int r = 0; r < 4; ++r)
            O[(lk * 4 + r) * 257 + w * 64 + n * 16 + lr] = pacc[n][r];
    __syncthreads();

    {
        const int row = tid >> 4;      // 16 rows, 16 threads each
        const int l16 = tid & 15;
        float* orow = O + row * 257;
        float s1 = 0.f;
        for (int i = l16; i < DMODEL; i += 16) s1 += orow[i];
#pragma unroll
        for (int off = 8; off; off >>= 1) s1 += __shfl_xor(s1, off);
        const float mu = s1 * (1.f / DMODEL);
        float s2 = 0.f;
        for (int i = l16; i < DMODEL; i += 16) {
            float d = orow[i] - mu;
            s2 += d * d;
        }
#pragma unroll
        for (int off = 8; off; off >>= 1) s2 += __shfl_xor(s2, off);
        const float rsig = rsqrtf(s2 * (1.f / DMODEL) + 1e-5f);
        float* grow = out + (size_t)(b * SRC + t_base + row) * DMODEL;
        for (int i = l16; i < DMODEL; i += 16)
            grow[i] = (orow[i] - mu) * rsig * gamma[i] + beta[i];
    }
}

extern "C" void kernel_launch(void* const* d_in, const int* in_sizes, int n_in,
                              void* d_out, int out_size, void* d_ws, size_t ws_size,
                              hipStream_t stream) {
    const float* mel      = (const float*)d_in[0];
    const float* text     = (const float*)d_in[1];
    const int*   mel_mask = (const int*)d_in[2];
    const int*   src_mask = (const int*)d_in[3];
    const float* Wq       = (const float*)d_in[4];
    const float* Wk       = (const float*)d_in[5];
    const float* Wv       = (const float*)d_in[6];
    const float* gamma    = (const float*)d_in[7];
    const float* beta     = (const float*)d_in[8];

    float* out      = (float*)d_out;
    float* attn_out = out + (size_t)BATCH * SRC * DMODEL;

    short* qbf = (short*)d_ws;                                   //  4 MB
    short* kbf = qbf + (size_t)BATCH * SRC * DMODEL;             // 16 MB
    short* vt  = kbf + (size_t)BATCH * MEL * DMODEL;             // 16 MB

    dim3 blk(256);
    // q = text @ Wq^T   -> [B*SRC][256] bf16
    proj_kernel<<<dim3(BATCH * SRC / 64, DMODEL / 64, 1), blk, 0, stream>>>(
        text, Wq, qbf, DMODEL, 0, 0, 0);
    // k = mel @ Wk^T    -> [B*MEL][256] bf16
    proj_kernel<<<dim3(BATCH * MEL / 64, DMODEL / 64, 1), blk, 0, stream>>>(
        mel, Wk, kbf, DMODEL, 0, 0, 0);
    // v^T = Wv @ mel^T  -> per batch [256][2048] bf16
    proj_kernel<<<dim3(DMODEL / 64, MEL / 64, BATCH), blk, 0, stream>>>(
        Wv, mel, vt, MEL, 0, (long)MEL * DMODEL, (long)DMODEL * MEL);

    attn_kernel<<<dim3(SRC / TB, BATCH), blk, 0, stream>>>(
        qbf, kbf, vt, mel_mask, src_mask, gamma, beta, out, attn_out);
}

// Round 5
// 306.198 us; speedup vs baseline: 1.4136x; 1.4136x over previous
//
#include <hip/hip_runtime.h>
#include <hip/hip_bf16.h>
#include <stdint.h>

#define DMODEL 256
#define BATCH  16
#define MEL    2048
#define SRC    512
#define TB     16
#define SP2    2056   // P_lds row stride (bf16 units): 4112B -> 4-bank row rotation, 2-way (free)

typedef __attribute__((ext_vector_type(8))) short bf16x8;
typedef __attribute__((ext_vector_type(4))) float f32x4;

__device__ inline short f2bf(float f) {
    union { float f; uint32_t u; } c{f};
    uint32_t u = c.u;
    u += 0x7FFFu + ((u >> 16) & 1u);   // RNE
    return (short)(u >> 16);
}

__device__ inline bf16x8 cvt8(const float* p) {
    const f32x4* q = reinterpret_cast<const f32x4*>(p);
    f32x4 a = q[0], b = q[1];
    bf16x8 r;
    r[0] = f2bf(a[0]); r[1] = f2bf(a[1]); r[2] = f2bf(a[2]); r[3] = f2bf(a[3]);
    r[4] = f2bf(b[0]); r[5] = f2bf(b[1]); r[6] = f2bf(b[2]); r[7] = f2bf(b[3]);
    return r;
}

// ---- convert Wq|Wk|Wv (each 256x256 f32) -> bf16, concatenated ----
__global__ __launch_bounds__(256)
void wconv_kernel(const float* __restrict__ Wq, const float* __restrict__ Wk,
                  const float* __restrict__ Wv, short* __restrict__ wb) {
    int i = blockIdx.x * 256 + threadIdx.x;        // 24576 threads, 8 elems each
    int which = i >> 13;
    int off = (i & 8191) * 8;
    const float* src = which == 0 ? Wq : (which == 1 ? Wk : Wv);
    *reinterpret_cast<bf16x8*>(wb + which * 65536 + off) = cvt8(src + off);
}

// ---- q = text @ Wq^T : A f32 (converted once/block), B bf16 ----
// grid.x = 8192/64 = 128 blocks, 256 threads (4 waves), wave = 16 rows x 256 cols
__global__ __launch_bounds__(256)
void qproj_kernel(const float* __restrict__ text, const short* __restrict__ Wqb,
                  short* __restrict__ qbf) {
    const int lane = threadIdx.x & 63, w = threadIdx.x >> 6;
    const int lr = lane & 15, lk = lane >> 4;
    const int row0 = blockIdx.x * 64 + w * 16;

    bf16x8 afr[8];
    const float* arow = text + (size_t)(row0 + lr) * DMODEL + 8 * lk;
#pragma unroll
    for (int t = 0; t < 8; ++t) afr[t] = cvt8(arow + 32 * t);

#pragma unroll
    for (int n = 0; n < 16; ++n) {
        f32x4 acc = {0.f, 0.f, 0.f, 0.f};
        const short* brow = Wqb + (size_t)(16 * n + lr) * DMODEL + 8 * lk;
#pragma unroll
        for (int t = 0; t < 8; ++t) {
            bf16x8 bfr = *reinterpret_cast<const bf16x8*>(brow + 32 * t);
            acc = __builtin_amdgcn_mfma_f32_16x16x32_bf16(afr[t], bfr, acc, 0, 0, 0);
        }
#pragma unroll
        for (int r = 0; r < 4; ++r)
            qbf[(size_t)(row0 + 4 * lk + r) * DMODEL + 16 * n + lr] = f2bf(acc[r]);
    }
}

// ---- fused K/V projection: per block, stage 64 mel rows (bf16) in LDS once;
//      compute k-tile [64x256] and vt-tile [256x64] from it ----
// grid (MEL/64, BATCH), 256 threads
__global__ __launch_bounds__(256)
void kvproj_kernel(const float* __restrict__ mel, const short* __restrict__ Wkb,
                   const short* __restrict__ Wvb, short* __restrict__ kbf,
                   short* __restrict__ vt) {
    __shared__ short mlds[64 * 264];   // 33,792 B; stride 264 -> 2-way-free reads

    const int tid = threadIdx.x;
    const int b = blockIdx.y, mr0 = blockIdx.x * 64;

    const float* gsrc = mel + (size_t)(b * MEL + mr0) * DMODEL;
#pragma unroll
    for (int i = 0; i < 8; ++i) {
        int row = (tid >> 5) + 8 * i, col = (tid & 31) * 8;
        *reinterpret_cast<bf16x8*>(&mlds[row * 264 + col]) = cvt8(gsrc + row * DMODEL + col);
    }
    __syncthreads();

    const int lane = tid & 63, w = tid >> 6;
    const int lr = lane & 15, lk = lane >> 4;

    // k-part: wave w -> mel rows [16w,16w+16), all 256 out cols
    bf16x8 afr[8];
#pragma unroll
    for (int t = 0; t < 8; ++t)
        afr[t] = *reinterpret_cast<const bf16x8*>(&mlds[(16 * w + lr) * 264 + 8 * lk + 32 * t]);
#pragma unroll
    for (int n = 0; n < 16; ++n) {
        f32x4 acc = {0.f, 0.f, 0.f, 0.f};
        const short* brow = Wkb + (size_t)(16 * n + lr) * DMODEL + 8 * lk;
#pragma unroll
        for (int t = 0; t < 8; ++t) {
            bf16x8 bfr = *reinterpret_cast<const bf16x8*>(brow + 32 * t);
            acc = __builtin_amdgcn_mfma_f32_16x16x32_bf16(afr[t], bfr, acc, 0, 0, 0);
        }
#pragma unroll
        for (int r = 0; r < 4; ++r)
            kbf[(size_t)(b * MEL + mr0 + 16 * w + 4 * lk + r) * DMODEL + 16 * n + lr] =
                f2bf(acc[r]);
    }

    // v-part: wave w -> vt rows [64w,64w+64), cols = this block's 64 mel rows
#pragma unroll
    for (int m = 0; m < 4; ++m) {
        bf16x8 a2[8];
        const short* arow2 = Wvb + (size_t)(64 * w + 16 * m + lr) * DMODEL + 8 * lk;
#pragma unroll
        for (int t = 0; t < 8; ++t)
            a2[t] = *reinterpret_cast<const bf16x8*>(arow2 + 32 * t);
#pragma unroll
        for (int n = 0; n < 4; ++n) {
            f32x4 acc = {0.f, 0.f, 0.f, 0.f};
#pragma unroll
            for (int t = 0; t < 8; ++t) {
                bf16x8 bfr = *reinterpret_cast<const bf16x8*>(
                    &mlds[(16 * n + lr) * 264 + 8 * lk + 32 * t]);
                acc = __builtin_amdgcn_mfma_f32_16x16x32_bf16(a2[t], bfr, acc, 0, 0, 0);
            }
#pragma unroll
            for (int r = 0; r < 4; ++r)
                vt[(size_t)(b * DMODEL + 64 * w + 16 * m + 4 * lk + r) * MEL +
                   mr0 + 16 * n + lr] = f2bf(acc[r]);
        }
    }
}

// ---- fused attention: 512 threads (8 waves), S register-resident,
//      register softmax, P staged bf16 in LDS for PV, fused LN ----
// grid (SRC/16, BATCH); LDS 66.8 KB -> 2 blocks/CU; VGPR capped for 4 waves/SIMD
__global__ __launch_bounds__(512, 4)
void attn_kernel(const short* __restrict__ qbf, const short* __restrict__ kbf,
                 const short* __restrict__ vt,
                 const int* __restrict__ mel_mask, const int* __restrict__ src_mask,
                 const float* __restrict__ gamma, const float* __restrict__ beta,
                 float* __restrict__ out, float* __restrict__ attn_out) {
    __shared__ short P[TB * SP2];     // 65,792 B
    __shared__ float red[2][TB][8];   // 1,024 B

    const int tid = threadIdx.x;
    const int lane = tid & 63, w = tid >> 6;
    const int lr = lane & 15, lk = lane >> 4;
    const int b = blockIdx.y, t_base = blockIdx.x * TB;
    const int c0 = w * 256;           // this wave's 256-col slice of mel

    // q fragments: A row = lane&15 = q-row
    bf16x8 qfr[8];
    const short* qrow = qbf + (size_t)(b * SRC + t_base + lr) * DMODEL + 8 * lk;
#pragma unroll
    for (int t = 0; t < 8; ++t)
        qfr[t] = *reinterpret_cast<const bf16x8*>(qrow + 32 * t);

    // ---- Phase 1: S = qk^T/16 + mel mask, register-resident ----
    f32x4 acc[16];
#pragma unroll
    for (int tile = 0; tile < 16; ++tile) {
        f32x4 a = {0.f, 0.f, 0.f, 0.f};
        const short* krow = kbf + (size_t)(b * MEL + c0 + tile * 16 + lr) * DMODEL + 8 * lk;
#pragma unroll
        for (int t = 0; t < 8; ++t) {
            bf16x8 kfr = *reinterpret_cast<const bf16x8*>(krow + 32 * t);
            a = __builtin_amdgcn_mfma_f32_16x16x32_bf16(qfr[t], kfr, a, 0, 0, 0);
        }
        const bool masked = mel_mask[b * MEL + c0 + tile * 16 + lr] != 0;
#pragma unroll
        for (int r = 0; r < 4; ++r)
            acc[tile][r] = masked ? -1e30f : a[r] * 0.0625f;
    }

    // ---- Phase 2: softmax. lane (lr,lk) holds rows {4lk+r} x cols {c0+16*tile+lr} ----
    float mr[4] = {-3.0e38f, -3.0e38f, -3.0e38f, -3.0e38f};
#pragma unroll
    for (int tile = 0; tile < 16; ++tile)
#pragma unroll
        for (int r = 0; r < 4; ++r) mr[r] = fmaxf(mr[r], acc[tile][r]);
#pragma unroll
    for (int off = 8; off; off >>= 1)
#pragma unroll
        for (int r = 0; r < 4; ++r) mr[r] = fmaxf(mr[r], __shfl_xor(mr[r], off));
    if (lr == 0) {
#pragma unroll
        for (int r = 0; r < 4; ++r) red[0][4 * lk + r][w] = mr[r];
    }
    __syncthreads();
    float M[4];
#pragma unroll
    for (int r = 0; r < 4; ++r) {
        float m = red[0][4 * lk + r][0];
#pragma unroll
        for (int j = 1; j < 8; ++j) m = fmaxf(m, red[0][4 * lk + r][j]);
        M[r] = m;
    }
    float sr[4] = {0.f, 0.f, 0.f, 0.f};
#pragma unroll
    for (int tile = 0; tile < 16; ++tile)
#pragma unroll
        for (int r = 0; r < 4; ++r) {
            float e = __expf(acc[tile][r] - M[r]);
            acc[tile][r] = e;
            sr[r] += e;
        }
#pragma unroll
    for (int off = 8; off; off >>= 1)
#pragma unroll
        for (int r = 0; r < 4; ++r) sr[r] += __shfl_xor(sr[r], off);
    if (lr == 0) {
#pragma unroll
        for (int r = 0; r < 4; ++r) red[1][4 * lk + r][w] = sr[r];
    }
    __syncthreads();
    float inv[4];
#pragma unroll
    for (int r = 0; r < 4; ++r) {
        float s = red[1][4 * lk + r][0];
#pragma unroll
        for (int j = 1; j < 8; ++j) s += red[1][4 * lk + r][j];
        inv[r] = src_mask[b * SRC + t_base + 4 * lk + r] ? 0.f : 1.f / s;
    }

    // ---- Phase 2b: write attn (f32, global) + P (bf16, LDS) ----
    float* abase = attn_out + (size_t)(b * SRC + t_base) * MEL;
#pragma unroll
    for (int tile = 0; tile < 16; ++tile) {
        const int col = c0 + tile * 16 + lr;
#pragma unroll
        for (int r = 0; r < 4; ++r) {
            float p = acc[tile][r] * inv[r];
            abase[(size_t)(4 * lk + r) * MEL + col] = p;
            P[(4 * lk + r) * SP2 + col] = f2bf(p);
        }
    }
    __syncthreads();

    // ---- Phase 3: PV. wave w -> out cols [32w, 32w+32) ----
    f32x4 pacc[2];
    pacc[0] = (f32x4){0.f, 0.f, 0.f, 0.f};
    pacc[1] = (f32x4){0.f, 0.f, 0.f, 0.f};
    for (int ks = 0; ks < MEL / 32; ++ks) {
        bf16x8 pa = *reinterpret_cast<const bf16x8*>(&P[lr * SP2 + 32 * ks + 8 * lk]);
#pragma unroll
        for (int n = 0; n < 2; ++n) {
            const short* vrow = vt + (size_t)(b * DMODEL + w * 32 + n * 16 + lr) * MEL +
                                32 * ks + 8 * lk;
            bf16x8 vfr = *reinterpret_cast<const bf16x8*>(vrow);
            pacc[n] = __builtin_amdgcn_mfma_f32_16x16x32_bf16(pa, vfr, pacc[n], 0, 0, 0);
        }
    }
    __syncthreads();

    // ---- Phase 4: LN. stage O in LDS (alias P), 32 threads/row ----
    float* O = reinterpret_cast<float*>(P);   // 16 x 264 f32 = 16.9 KB
#pragma unroll
    for (int n = 0; n < 2; ++n)
#pragma unroll
        for (int r = 0; r < 4; ++r)
            O[(4 * lk + r) * 264 + w * 32 + n * 16 + lr] = pacc[n][r];
    __syncthreads();

    {
        const int row = tid >> 5, l = tid & 31;
        const float* orow = O + row * 264;
        float s1 = 0.f;
#pragma unroll
        for (int j = 0; j < 8; ++j) s1 += orow[l + 32 * j];
#pragma unroll
        for (int off = 16; off; off >>= 1) s1 += __shfl_xor(s1, off);
        const float mu = s1 * (1.f / DMODEL);
        float s2 = 0.f;
#pragma unroll
        for (int j = 0; j < 8; ++j) {
            float d = orow[l + 32 * j] - mu;
            s2 += d * d;
        }
#pragma unroll
        for (int off = 16; off; off >>= 1) s2 += __shfl_xor(s2, off);
        const float rsig = rsqrtf(s2 * (1.f / DMODEL) + 1e-5f);
        float* g = out + (size_t)(b * SRC + t_base + row) * DMODEL;
#pragma unroll
        for (int j = 0; j < 8; ++j) {
            int i = l + 32 * j;
            g[i] = (orow[i] - mu) * rsig * gamma[i] + beta[i];
        }
    }
}

extern "C" void kernel_launch(void* const* d_in, const int* in_sizes, int n_in,
                              void* d_out, int out_size, void* d_ws, size_t ws_size,
                              hipStream_t stream) {
    const float* mel      = (const float*)d_in[0];
    const float* text     = (const float*)d_in[1];
    const int*   mel_mask = (const int*)d_in[2];
    const int*   src_mask = (const int*)d_in[3];
    const float* Wq       = (const float*)d_in[4];
    const float* Wk       = (const float*)d_in[5];
    const float* Wv       = (const float*)d_in[6];
    const float* gamma    = (const float*)d_in[7];
    const float* beta     = (const float*)d_in[8];

    float* out      = (float*)d_out;
    float* attn_out = out + (size_t)BATCH * SRC * DMODEL;

    short* wb  = (short*)d_ws;                        // 3 x 65536 bf16 = 384 KB
    short* Wqb = wb;
    short* Wkb = wb + 65536;
    short* Wvb = wb + 131072;
    short* qbf = wb + 3 * 65536;                      // 4 MB
    short* kbf = qbf + (size_t)BATCH * SRC * DMODEL;  // 16 MB
    short* vt  = kbf + (size_t)BATCH * MEL * DMODEL;  // 16 MB

    wconv_kernel<<<96, 256, 0, stream>>>(Wq, Wk, Wv, wb);
    qproj_kernel<<<BATCH * SRC / 64, 256, 0, stream>>>(text, Wqb, qbf);
    kvproj_kernel<<<dim3(MEL / 64, BATCH), 256, 0, stream>>>(mel, Wkb, Wvb, kbf, vt);
    attn_kernel<<<dim3(SRC / TB, BATCH), 512, 0, stream>>>(
        qbf, kbf, vt, mel_mask, src_mask, gamma, beta, out, attn_out);
}